// Round 1
// baseline (400.682 us; speedup 1.0000x reference)
//
#include <hip/hip_runtime.h>
#include <hip/hip_cooperative_groups.h>
#include <math.h>

// ---------------------------------------------------------------------------
// YOLOv5-style loss, 3 layers, fp32.
// R5: our 4 device kernels each run well under the 61us harness poison fill
// (none in rocprof top-5) yet dur_us=230. Theory: the time is dominated by
// dispatch serialization (memset -> entry -> scan -> final, each a full
// drain on tiny 82/394-block grids), not device work (~100MB line traffic
// ~= 16-30us). Fix: single cooperative kernel, phases separated by
// grid.sync(): zero -> entry -> {winner-correction by entry threads (they
// still hold ciou/x_obj in regs; scan no longer reads winner/iou) || scan}
// -> final. 5 dispatches -> 1. Fallback to the proven 4-dispatch path if
// cooperative launch is rejected.
// ---------------------------------------------------------------------------

#define EPS 1e-7f
#define BS 16
#define NA 3
#define NC 80

#define LOG2E 1.44269504088896340736f
#define LN2   0.69314718055994530942f

struct Layer {
    const float* pred;
    const int*   b;
    const int*   a;
    const int*   gj;
    const int*   gi;
    const int*   tcls;
    const float* tbox;
    const float* anc;
    unsigned int* winner;   // [48*g*g] cells, 0 = empty else entry_idx+1
    unsigned int* cnt;      // [48*g*g] entry multiplicity per cell
    float*        iou;      // [n] CIoU per entry (fallback path only)
    int g;
    int n;
};

struct Args {
    Layer L[3];
    int cum0;               // fallback kernels: block partition
    int cum1;
    int ecum0, ecum1, etot; // fused: entry-phase cumulative blocks
    int scum0, scum1;       // fused: scan-phase cumulative blocks
    uint4* zbase;           // zero region (acc + winner + cnt)
    int    zvec;            // #uint4 to zero
};

__device__ __forceinline__ int pick_layer(const Args& A, int& lb) {
    int bid = blockIdx.x;
    if (bid < A.cum0) { lb = bid; return 0; }
    if (bid < A.cum1) { lb = bid - A.cum0; return 1; }
    lb = bid - A.cum1; return 2;
}

// reduce two independent sums across a 256-thread block.
// Leading __syncthreads makes back-to-back calls in one kernel safe.
__device__ __forceinline__ void block_reduce256_2(float& a, float& b) {
    __shared__ float sma[4], smb[4];
    __syncthreads();
    #pragma unroll
    for (int o = 32; o > 0; o >>= 1) {
        a += __shfl_down(a, o, 64);
        b += __shfl_down(b, o, 64);
    }
    int lane = threadIdx.x & 63;
    int wid  = threadIdx.x >> 6;
    if (lane == 0) { sma[wid] = a; smb[wid] = b; }
    __syncthreads();
    if (threadIdx.x == 0) {
        a = sma[0] + sma[1] + sma[2] + sma[3];
        b = smb[0] + smb[1] + smb[2] + smb[3];
    }
}

// bce_with_logits(x, 0) via HW transcendentals: branchless, ~7 VALU ops
__device__ __forceinline__ float bce0(float x) {
    float t = __builtin_amdgcn_exp2f(-fabsf(x) * LOG2E);   // exp(-|x|)
    return fmaxf(x, 0.f) + LN2 * __builtin_amdgcn_logf(1.f + t);
}

// sigmoid via HW exp2 + rcp
__device__ __forceinline__ float fsigmoid(float x) {
    float e = __builtin_amdgcn_exp2f(-x * LOG2E);
    return __builtin_amdgcn_rcpf(1.f + e);
}

// ===========================================================================
// Fused single-dispatch cooperative kernel
// ===========================================================================
__global__ void __launch_bounds__(256) fused_kernel(Args A, float* acc, float* out) {
    const int tid  = threadIdx.x;
    const int bid  = blockIdx.x;
    const int nthr = (int)gridDim.x * 256;
    cooperative_groups::grid_group grid = cooperative_groups::this_grid();

    // ---- phase 0: zero acc + winner + cnt (grid-stride uint4) ----
    {
        uint4 z = make_uint4(0u, 0u, 0u, 0u);
        for (int i = bid * 256 + tid; i < A.zvec; i += nthr) A.zbase[i] = z;
    }
    grid.sync();

    // ---- phase 1: per-entry CIoU + box + scatter + class-positive gather --
    float ciou = 0.f, xobj = 0.f;
    int   cell = -1, j = -1, layer = 0;
    if (bid < A.etot) {
        int lb;
        if (bid < A.ecum0)      { layer = 0; lb = bid; }
        else if (bid < A.ecum1) { layer = 1; lb = bid - A.ecum0; }
        else                    { layer = 2; lb = bid - A.ecum1; }
        const Layer& L = A.L[layer];
        j = lb * 256 + tid;
        float box_c = 0.f, neg_c = 0.f;
        if (j < L.n) {
            int b  = L.b[j],  a  = L.a[j];
            int gy = L.gj[j], gx = L.gi[j];
            int g = L.g, gg = g * g;
            int q = b * NA + a;
            const float* base = L.pred + ((size_t)(q * 85) * gg + (size_t)gy * g + gx);
            float px = base[0];
            float py = base[gg];
            float pw = base[2 * (size_t)gg];
            float ph = base[3 * (size_t)gg];
            xobj     = base[4 * (size_t)gg];
            // decode
            float cx = 2.f * fsigmoid(px) - 0.5f;
            float cy = 2.f * fsigmoid(py) - 0.5f;
            float sw = 2.f * fsigmoid(pw);
            float sh = 2.f * fsigmoid(ph);
            float bw = sw * sw * L.anc[2 * j];
            float bh = sh * sh * L.anc[2 * j + 1];
            float fg = (float)g;
            float tx = L.tbox[4 * j + 0] * fg - (float)gx;
            float ty = L.tbox[4 * j + 1] * fg - (float)gy;
            float tw = L.tbox[4 * j + 2] * fg;
            float th = L.tbox[4 * j + 3] * fg;
            // CIoU
            float b1x1 = cx - bw * 0.5f, b1x2 = cx + bw * 0.5f;
            float b1y1 = cy - bh * 0.5f, b1y2 = cy + bh * 0.5f;
            float b2x1 = tx - tw * 0.5f, b2x2 = tx + tw * 0.5f;
            float b2y1 = ty - th * 0.5f, b2y2 = ty + th * 0.5f;
            float iw = fminf(b1x2, b2x2) - fmaxf(b1x1, b2x1);
            float ih = fminf(b1y2, b2y2) - fmaxf(b1y1, b2y1);
            float inter = fmaxf(iw, 0.f) * fmaxf(ih, 0.f);
            float w1 = b1x2 - b1x1, h1 = b1y2 - b1y1 + EPS;
            float w2 = b2x2 - b2x1, h2 = b2y2 - b2y1 + EPS;
            float uni = w1 * h1 + w2 * h2 - inter + EPS;
            float iou = inter / uni;
            float cw  = fmaxf(b1x2, b2x2) - fminf(b1x1, b2x1);
            float chh = fmaxf(b1y2, b2y2) - fminf(b1y1, b2y1);
            float c2  = cw * cw + chh * chh + EPS;
            float dx = b2x1 + b2x2 - b1x1 - b1x2;
            float dy = b2y1 + b2y2 - b1y1 - b1y2;
            float rho2 = (dx * dx + dy * dy) * 0.25f;
            float dv = atanf(w2 / h2) - atanf(w1 / h1);
            float v = (4.f / (float)(M_PI * M_PI)) * dv * dv;
            float alpha = v / (v - iou + (1.f + EPS));
            ciou = iou - (rho2 / c2 + v * alpha);
            cell = q * gg + gy * g + gx;
            atomicMax(&L.winner[cell], (unsigned int)(j + 1));
            atomicAdd(&L.cnt[cell], 1u);
            box_c = 1.f - ciou;
            // class positive term: bce(x,1) = bce(x,0) - x  -> subtract x[tcls]
            neg_c = base[(size_t)(5 + L.tcls[j]) * gg];
        }
        block_reduce256_2(box_c, neg_c);
        if (tid == 0) {
            atomicAdd(&acc[0 + layer], box_c);
            atomicAdd(&acc[6 + layer], -neg_c);
        }
    }
    grid.sync();   // winner/cnt now final everywhere

    // ---- phase 1b: obj winner-correction, paid by entry threads -----------
    // (ciou & x_obj still live in registers; scan never touches winner/iou)
    if (bid < A.etot) {
        float corr = 0.f;
        if (cell >= 0 && A.L[layer].winner[cell] == (unsigned int)(j + 1))
            corr = xobj * fmaxf(ciou, 0.f);
        float dummy = 0.f;
        block_reduce256_2(corr, dummy);
        if (tid == 0 && corr != 0.f) atomicAdd(&acc[3 + layer], -corr);
    }

    // ---- phase 2: cnt-gated channel scan (no winner/iou reads) ------------
    {
        int lb, sl;
        if (bid < A.scum0)      { sl = 0; lb = bid; }
        else if (bid < A.scum1) { sl = 1; lb = bid - A.scum0; }
        else                    { sl = 2; lb = bid - A.scum1; }
        const Layer L = A.L[sl];
        int gg = L.g * L.g;
        int cells = BS * NA * gg;
        int ci = lb * 1024 + tid * 4;
        float obj_s = 0.f, cls_s = 0.f;
        if (ci < cells) {
            int q = ci / gg;
            int e = ci - q * gg;
            uint4 c4 = *(const uint4*)(L.cnt + ci);
            const float* pbase = L.pred + (size_t)(q * 85 + 4) * gg + e;
            float4 x4 = *(const float4*)pbase;           // objectness channel
            obj_s = bce0(x4.x) + bce0(x4.y) + bce0(x4.z) + bce0(x4.w);
            if (c4.x | c4.y | c4.z | c4.w) {
                float f0 = (float)c4.x, f1 = (float)c4.y;
                float f2 = (float)c4.z, f3 = (float)c4.w;
                const float* p = pbase + gg;
                float s0 = 0.f, s1 = 0.f;
                #pragma unroll 8
                for (int r = 0; r < NC; r += 2) {
                    float4 ya = *(const float4*)(p + (size_t)r * gg);
                    float4 yb = *(const float4*)(p + (size_t)(r + 1) * gg);
                    s0 += f0 * bce0(ya.x) + f1 * bce0(ya.y)
                        + f2 * bce0(ya.z) + f3 * bce0(ya.w);
                    s1 += f0 * bce0(yb.x) + f1 * bce0(yb.y)
                        + f2 * bce0(yb.z) + f3 * bce0(yb.w);
                }
                cls_s = s0 + s1;
            }
        }
        block_reduce256_2(obj_s, cls_s);
        if (tid == 0) {
            if (obj_s != 0.f) atomicAdd(&acc[3 + sl], obj_s);
            if (cls_s != 0.f) atomicAdd(&acc[6 + sl], cls_s);
        }
    }
    grid.sync();

    // ---- phase 3: combine -------------------------------------------------
    if (bid == 0 && tid == 0) {
        float n0 = (float)A.L[0].n, n1 = (float)A.L[1].n, n2 = (float)A.L[2].n;
        float c0 = (float)(BS * NA * A.L[0].g * A.L[0].g);
        float c1 = (float)(BS * NA * A.L[1].g * A.L[1].g);
        float c2 = (float)(BS * NA * A.L[2].g * A.L[2].g);
        float box_l = acc[0] / n0 + acc[1] / n1 + acc[2] / n2;
        float obj_l = 0.4f * acc[3] / c0 + 1.0f * acc[4] / c1 + 4.0f * acc[5] / c2;
        float cls_l = acc[6] / (n0 * NC) + acc[7] / (n1 * NC) + acc[8] / (n2 * NC);
        out[0] = 0.05f * box_l + 1.0f * obj_l + 0.5f * cls_l;
    }
}

// ===========================================================================
// Fallback path: the proven 4-dispatch pipeline (unchanged from R4)
// ===========================================================================
__global__ void entry_kernel(Args A, float* acc) {
    int lb; int layer = pick_layer(A, lb);
    const Layer L = A.L[layer];
    int j = lb * 256 + (int)threadIdx.x;
    float box_c = 0.f;
    float neg_c = 0.f;
    if (j < L.n) {
        int b  = L.b[j],  a  = L.a[j];
        int gy = L.gj[j], gx = L.gi[j];
        int g = L.g, gg = g * g;
        int q = b * NA + a;
        const float* base = L.pred + ((size_t)(q * 85) * gg + (size_t)gy * g + gx);
        float px = base[0];
        float py = base[gg];
        float pw = base[2 * (size_t)gg];
        float ph = base[3 * (size_t)gg];
        float cx = 2.f * fsigmoid(px) - 0.5f;
        float cy = 2.f * fsigmoid(py) - 0.5f;
        float sw = 2.f * fsigmoid(pw);
        float sh = 2.f * fsigmoid(ph);
        float bw = sw * sw * L.anc[2 * j];
        float bh = sh * sh * L.anc[2 * j + 1];
        float fg = (float)g;
        float tx = L.tbox[4 * j + 0] * fg - (float)gx;
        float ty = L.tbox[4 * j + 1] * fg - (float)gy;
        float tw = L.tbox[4 * j + 2] * fg;
        float th = L.tbox[4 * j + 3] * fg;
        float b1x1 = cx - bw * 0.5f, b1x2 = cx + bw * 0.5f;
        float b1y1 = cy - bh * 0.5f, b1y2 = cy + bh * 0.5f;
        float b2x1 = tx - tw * 0.5f, b2x2 = tx + tw * 0.5f;
        float b2y1 = ty - th * 0.5f, b2y2 = ty + th * 0.5f;
        float iw = fminf(b1x2, b2x2) - fmaxf(b1x1, b2x1);
        float ih = fminf(b1y2, b2y2) - fmaxf(b1y1, b2y1);
        float inter = fmaxf(iw, 0.f) * fmaxf(ih, 0.f);
        float w1 = b1x2 - b1x1, h1 = b1y2 - b1y1 + EPS;
        float w2 = b2x2 - b2x1, h2 = b2y2 - b2y1 + EPS;
        float uni = w1 * h1 + w2 * h2 - inter + EPS;
        float iou = inter / uni;
        float cw  = fmaxf(b1x2, b2x2) - fminf(b1x1, b2x1);
        float chh = fmaxf(b1y2, b2y2) - fminf(b1y1, b2y1);
        float c2  = cw * cw + chh * chh + EPS;
        float dx = b2x1 + b2x2 - b1x1 - b1x2;
        float dy = b2y1 + b2y2 - b1y1 - b1y2;
        float rho2 = (dx * dx + dy * dy) * 0.25f;
        float dv = atanf(w2 / h2) - atanf(w1 / h1);
        float v = (4.f / (float)(M_PI * M_PI)) * dv * dv;
        float alpha = v / (v - iou + (1.f + EPS));
        float ciou = iou - (rho2 / c2 + v * alpha);
        L.iou[j] = ciou;
        int cell = q * gg + gy * g + gx;
        atomicMax(&L.winner[cell], (unsigned int)(j + 1));
        atomicAdd(&L.cnt[cell], 1u);
        box_c = 1.f - ciou;
        neg_c = base[(size_t)(5 + L.tcls[j]) * gg];
    }
    block_reduce256_2(box_c, neg_c);
    if (threadIdx.x == 0) {
        atomicAdd(&acc[0 + layer], box_c);
        atomicAdd(&acc[6 + layer], -neg_c);
    }
}

__global__ void scan_kernel(Args A, float* acc) {
    int lb; int layer = pick_layer(A, lb);
    const Layer L = A.L[layer];
    int gg = L.g * L.g;
    int cells = BS * NA * gg;
    int ci = lb * 1024 + (int)threadIdx.x * 4;
    float obj_s = 0.f, cls_s = 0.f;
    if (ci < cells) {
        int q = ci / gg;
        int e = ci - q * gg;
        uint4 c4 = *(const uint4*)(L.cnt + ci);
        uint4 w4 = *(const uint4*)(L.winner + ci);
        const float* pbase = L.pred + (size_t)(q * 85 + 4) * gg + e;
        float4 x4 = *(const float4*)pbase;
        obj_s = bce0(x4.x) + bce0(x4.y) + bce0(x4.z) + bce0(x4.w);
        if (w4.x) obj_s -= x4.x * fmaxf(L.iou[w4.x - 1], 0.f);
        if (w4.y) obj_s -= x4.y * fmaxf(L.iou[w4.y - 1], 0.f);
        if (w4.z) obj_s -= x4.z * fmaxf(L.iou[w4.z - 1], 0.f);
        if (w4.w) obj_s -= x4.w * fmaxf(L.iou[w4.w - 1], 0.f);
        if (c4.x | c4.y | c4.z | c4.w) {
            float f0 = (float)c4.x, f1 = (float)c4.y;
            float f2 = (float)c4.z, f3 = (float)c4.w;
            const float* p = pbase + gg;
            #pragma unroll 8
            for (int r = 0; r < NC; ++r) {
                float4 y = *(const float4*)(p + (size_t)r * gg);
                cls_s += f0 * bce0(y.x) + f1 * bce0(y.y)
                       + f2 * bce0(y.z) + f3 * bce0(y.w);
            }
        }
    }
    block_reduce256_2(obj_s, cls_s);
    if (threadIdx.x == 0) {
        if (obj_s != 0.f) atomicAdd(&acc[3 + layer], obj_s);
        if (cls_s != 0.f) atomicAdd(&acc[6 + layer], cls_s);
    }
}

__global__ void final_kernel(const float* acc, float* out,
                             int n0, int n1, int n2,
                             int c0, int c1, int c2) {
    float box_l = acc[0] / (float)n0 + acc[1] / (float)n1 + acc[2] / (float)n2;
    float obj_l = 0.4f * acc[3] / (float)c0
                + 1.0f * acc[4] / (float)c1
                + 4.0f * acc[5] / (float)c2;
    float cls_l = acc[6] / ((float)n0 * NC)
                + acc[7] / ((float)n1 * NC)
                + acc[8] / ((float)n2 * NC);
    out[0] = 0.05f * box_l + 1.0f * obj_l + 0.5f * cls_l;
}

extern "C" void kernel_launch(void* const* d_in, const int* in_sizes, int n_in,
                              void* d_out, int out_size, void* d_ws, size_t ws_size,
                              hipStream_t stream) {
    (void)n_in; (void)out_size; (void)ws_size;
    char* ws = (char*)d_ws;

    Args A;
    int n[3], g[3], cells[3];
    size_t off = 64;                       // bytes 0..63: 9 float accumulators
    size_t winner_off[3], cnt_off[3], iou_off[3];

    for (int i = 0; i < 3; ++i) {
        n[i] = in_sizes[8 * i + 1];
        int gg = in_sizes[8 * i] / (BS * 255);
        int gv = (int)(sqrt((double)gg) + 0.5);
        g[i] = gv;
        cells[i] = BS * NA * gv * gv;
        winner_off[i] = off; off += (size_t)cells[i] * 4;
        cnt_off[i]    = off; off += (size_t)cells[i] * 4;
    }
    size_t zero_bytes = off;               // accumulators + winner + cnt
    for (int i = 0; i < 3; ++i) { iou_off[i] = off; off += (size_t)n[i] * 4; }

    for (int i = 0; i < 3; ++i) {
        Layer& L = A.L[i];
        L.pred = (const float*)d_in[8 * i + 0];
        L.b    = (const int*)  d_in[8 * i + 1];
        L.a    = (const int*)  d_in[8 * i + 2];
        L.gj   = (const int*)  d_in[8 * i + 3];
        L.gi   = (const int*)  d_in[8 * i + 4];
        L.tbox = (const float*)d_in[8 * i + 5];
        L.tcls = (const int*)  d_in[8 * i + 6];
        L.anc  = (const float*)d_in[8 * i + 7];
        L.winner = (unsigned int*)(ws + winner_off[i]);
        L.cnt    = (unsigned int*)(ws + cnt_off[i]);
        L.iou    = (float*)(ws + iou_off[i]);
        L.g = g[i];
        L.n = n[i];
    }
    float* acc = (float*)ws;
    float* outp = (float*)d_out;

    int e[3], s[3];
    for (int i = 0; i < 3; ++i) {
        e[i] = (n[i] + 255) / 256;
        s[i] = (cells[i] + 1023) / 1024;
    }
    A.ecum0 = e[0]; A.ecum1 = e[0] + e[1]; A.etot = e[0] + e[1] + e[2];
    A.scum0 = s[0]; A.scum1 = s[0] + s[1];
    int grid = s[0] + s[1] + s[2];
    if (A.etot > grid) grid = A.etot;
    A.zbase = (uint4*)ws;
    A.zvec  = (int)(zero_bytes / 16);      // 64B header + cells*8, both 16B-multiples
    A.cum0 = 0; A.cum1 = 0;

    void* kargs[] = { (void*)&A, (void*)&acc, (void*)&outp };
    hipError_t err = hipLaunchCooperativeKernel((void*)fused_kernel,
                                                dim3(grid), dim3(256),
                                                kargs, 0, stream);
    if (err != hipSuccess) {
        // proven 4-dispatch fallback
        hipMemsetAsync(d_ws, 0, zero_bytes, stream);
        A.cum0 = e[0]; A.cum1 = e[0] + e[1];
        entry_kernel<<<e[0] + e[1] + e[2], 256, 0, stream>>>(A, acc);
        A.cum0 = s[0]; A.cum1 = s[0] + s[1];
        scan_kernel<<<s[0] + s[1] + s[2], 256, 0, stream>>>(A, acc);
        final_kernel<<<1, 1, 0, stream>>>(acc, outp,
                                          n[0], n[1], n[2],
                                          cells[0], cells[1], cells[2]);
    }
}

// Round 2
// 230.295 us; speedup vs baseline: 1.7399x; 1.7399x over previous
//
#include <hip/hip_runtime.h>
#include <math.h>

// ---------------------------------------------------------------------------
// YOLOv5-style loss, 3 layers, fp32.
// R6: cooperative fusion (R5) regressed badly: +150us harness overhead and
// the fused kernel itself was 188us, hbm 343 GB/s / VALU 4.5% / occ 18% =
// latency-bound. Root cause exposed: sparse per-lane gating of class loads
// de-coalesces them (~10 scattered 64B lines per wave-instr) and 394 blocks
// give only ~1.4 waves/SIMD. Since every 256-cell wave span contains an
// active cell, sparsity saves nothing at wave level. New scan: DENSE class
// read (all lanes load, multiply by cnt, 0 for inactive), 80 channels split
// into 8 chunks of 10 -> 3152 blocks (~12/CU), fully-coalesced 129MB at BW
// instead of 58MB scattered at 343 GB/s. Obj+winner correction folded into
// chunk 0. Partial-sum atomics spread over 32 slots/(layer,quantity).
// Structure back to proven 4 dispatches: memset -> entry -> scan -> final.
// ---------------------------------------------------------------------------

#define EPS 1e-7f
#define BS 16
#define NA 3
#define NC 80

#define LOG2E 1.44269504088896340736f
#define LN2   0.69314718055994530942f

// accumulator layout (floats): [0..2]=box  [3..98]=obj 3x32  [99..194]=cls 3x32
#define ACC_OBJ 3
#define ACC_CLS 99
#define ACC_FLOATS 256          // rounded; header = 1024 bytes

struct Layer {
    const float* pred;
    const int*   b;
    const int*   a;
    const int*   gj;
    const int*   gi;
    const int*   tcls;
    const float* tbox;
    const float* anc;
    unsigned int* winner;   // [48*g*g] cells, 0 = empty else entry_idx+1
    unsigned int* cnt;      // [48*g*g] entry multiplicity per cell
    float*        iou;      // [n] CIoU per entry
    int g;
    int n;
};

struct Args {
    Layer L[3];
    int cum0;   // block-partition boundaries for the current launch
    int cum1;
};

__device__ __forceinline__ int pick_layer(const Args& A, int& lb) {
    int bid = blockIdx.x;
    if (bid < A.cum0) { lb = bid; return 0; }
    if (bid < A.cum1) { lb = bid - A.cum0; return 1; }
    lb = bid - A.cum1; return 2;
}

// reduce two independent sums across a 256-thread block
__device__ __forceinline__ void block_reduce256_2(float& a, float& b) {
    #pragma unroll
    for (int o = 32; o > 0; o >>= 1) {
        a += __shfl_down(a, o, 64);
        b += __shfl_down(b, o, 64);
    }
    __shared__ float sma[4], smb[4];
    int lane = threadIdx.x & 63;
    int wid  = threadIdx.x >> 6;
    if (lane == 0) { sma[wid] = a; smb[wid] = b; }
    __syncthreads();
    if (threadIdx.x == 0) {
        a = sma[0] + sma[1] + sma[2] + sma[3];
        b = smb[0] + smb[1] + smb[2] + smb[3];
    }
}

// bce_with_logits(x, 0) via HW transcendentals: branchless, ~7 VALU ops
__device__ __forceinline__ float bce0(float x) {
    float t = __builtin_amdgcn_exp2f(-fabsf(x) * LOG2E);   // exp(-|x|)
    return fmaxf(x, 0.f) + LN2 * __builtin_amdgcn_logf(1.f + t);
}

// sigmoid via HW exp2 + rcp
__device__ __forceinline__ float fsigmoid(float x) {
    float e = __builtin_amdgcn_exp2f(-x * LOG2E);
    return __builtin_amdgcn_rcpf(1.f + e);
}

// --- kernel 1: per-entry CIoU + box loss + winner/cnt scatter + tcls gather -
__global__ void entry_kernel(Args A, float* acc) {
    int lb; int layer = pick_layer(A, lb);
    const Layer L = A.L[layer];
    int j = lb * 256 + (int)threadIdx.x;
    float box_c = 0.f;
    float neg_c = 0.f;    // x[tcls] to subtract from cls sum
    if (j < L.n) {
        int b  = L.b[j],  a  = L.a[j];
        int gy = L.gj[j], gx = L.gi[j];
        int g = L.g, gg = g * g;
        int q = b * NA + a;
        const float* base = L.pred + ((size_t)(q * 85) * gg + (size_t)gy * g + gx);
        float px = base[0];
        float py = base[gg];
        float pw = base[2 * (size_t)gg];
        float ph = base[3 * (size_t)gg];
        // decode
        float cx = 2.f * fsigmoid(px) - 0.5f;
        float cy = 2.f * fsigmoid(py) - 0.5f;
        float sw = 2.f * fsigmoid(pw);
        float sh = 2.f * fsigmoid(ph);
        float bw = sw * sw * L.anc[2 * j];
        float bh = sh * sh * L.anc[2 * j + 1];
        float fg = (float)g;
        float tx = L.tbox[4 * j + 0] * fg - (float)gx;
        float ty = L.tbox[4 * j + 1] * fg - (float)gy;
        float tw = L.tbox[4 * j + 2] * fg;
        float th = L.tbox[4 * j + 3] * fg;
        // CIoU
        float b1x1 = cx - bw * 0.5f, b1x2 = cx + bw * 0.5f;
        float b1y1 = cy - bh * 0.5f, b1y2 = cy + bh * 0.5f;
        float b2x1 = tx - tw * 0.5f, b2x2 = tx + tw * 0.5f;
        float b2y1 = ty - th * 0.5f, b2y2 = ty + th * 0.5f;
        float iw = fminf(b1x2, b2x2) - fmaxf(b1x1, b2x1);
        float ih = fminf(b1y2, b2y2) - fmaxf(b1y1, b2y1);
        float inter = fmaxf(iw, 0.f) * fmaxf(ih, 0.f);
        float w1 = b1x2 - b1x1, h1 = b1y2 - b1y1 + EPS;
        float w2 = b2x2 - b2x1, h2 = b2y2 - b2y1 + EPS;
        float uni = w1 * h1 + w2 * h2 - inter + EPS;
        float iou = inter / uni;
        float cw  = fmaxf(b1x2, b2x2) - fminf(b1x1, b2x1);
        float chh = fmaxf(b1y2, b2y2) - fminf(b1y1, b2y1);
        float c2  = cw * cw + chh * chh + EPS;
        float dx = b2x1 + b2x2 - b1x1 - b1x2;
        float dy = b2y1 + b2y2 - b1y1 - b1y2;
        float rho2 = (dx * dx + dy * dy) * 0.25f;
        float dv = atanf(w2 / h2) - atanf(w1 / h1);
        float v = (4.f / (float)(M_PI * M_PI)) * dv * dv;
        float alpha = v / (v - iou + (1.f + EPS));
        float ciou = iou - (rho2 / c2 + v * alpha);
        L.iou[j] = ciou;
        int cell = q * gg + gy * g + gx;
        atomicMax(&L.winner[cell], (unsigned int)(j + 1));
        atomicAdd(&L.cnt[cell], 1u);
        box_c = 1.f - ciou;
        // class positive term: bce(x,1) = bce(x,0) - x  -> subtract x[tcls]
        neg_c = base[(size_t)(5 + L.tcls[j]) * gg];
    }
    block_reduce256_2(box_c, neg_c);
    if (threadIdx.x == 0) {
        atomicAdd(&acc[layer], box_c);
        atomicAdd(&acc[ACC_CLS + layer * 32 + (blockIdx.x & 31)], -neg_c);
    }
}

// --- kernel 2: DENSE channel scan, 10 channels per block ------------------
// Thread owns 4 consecutive cells (float4 column). Block = (cell-group,
// channel-chunk). All lanes load every channel (fully coalesced 1KB/wave);
// weight cnt (0 for inactive cells) makes inactive contributions vanish.
// Chunk 0 additionally handles objectness + winner correction.
__global__ void scan_kernel(Args A, float* acc) {
    int lb; int layer = pick_layer(A, lb);
    const Layer L = A.L[layer];
    int gg = L.g * L.g;
    int cells = BS * NA * gg;
    int sb = (cells + 1023) >> 10;       // cell groups per chunk
    int group = lb % sb;                 // consecutive blocks -> consecutive groups
    int chunk = lb / sb;                 // 0..7, channels 5+10c .. 5+10c+10
    int ci = group * 1024 + (int)threadIdx.x * 4;
    float obj_s = 0.f, cls_s = 0.f;
    if (ci < cells) {
        int q = ci / gg;
        int e = ci - q * gg;
        uint4 c4 = *(const uint4*)(L.cnt + ci);
        const float* pbase = L.pred + (size_t)(q * 85) * gg + e;
        float f0 = (float)c4.x, f1 = (float)c4.y;
        float f2 = (float)c4.z, f3 = (float)c4.w;
        const float* p = pbase + (size_t)(5 + 10 * chunk) * gg;
        float s0 = 0.f, s1 = 0.f;
        #pragma unroll
        for (int r = 0; r < 10; r += 2) {
            float4 ya = *(const float4*)(p + (size_t)r * gg);
            float4 yb = *(const float4*)(p + (size_t)(r + 1) * gg);
            s0 += f0 * bce0(ya.x) + f1 * bce0(ya.y)
                + f2 * bce0(ya.z) + f3 * bce0(ya.w);
            s1 += f0 * bce0(yb.x) + f1 * bce0(yb.y)
                + f2 * bce0(yb.z) + f3 * bce0(yb.w);
        }
        cls_s = s0 + s1;
        if (chunk == 0) {
            uint4 w4 = *(const uint4*)(L.winner + ci);
            float4 x4 = *(const float4*)(pbase + 4 * (size_t)gg);
            obj_s = bce0(x4.x) + bce0(x4.y) + bce0(x4.z) + bce0(x4.w);
            if (w4.x) obj_s -= x4.x * fmaxf(L.iou[w4.x - 1], 0.f);
            if (w4.y) obj_s -= x4.y * fmaxf(L.iou[w4.y - 1], 0.f);
            if (w4.z) obj_s -= x4.z * fmaxf(L.iou[w4.z - 1], 0.f);
            if (w4.w) obj_s -= x4.w * fmaxf(L.iou[w4.w - 1], 0.f);
        }
    }
    block_reduce256_2(obj_s, cls_s);
    if (threadIdx.x == 0) {
        int s = blockIdx.x & 31;
        if (chunk == 0)    atomicAdd(&acc[ACC_OBJ + layer * 32 + s], obj_s);
        if (cls_s != 0.f)  atomicAdd(&acc[ACC_CLS + layer * 32 + s], cls_s);
    }
}

// --- kernel 3: combine ------------------------------------------------------
__global__ void final_kernel(const float* acc, float* out,
                             int n0, int n1, int n2,
                             int c0, int c1, int c2) {
    float obj[3] = {0.f, 0.f, 0.f};
    float cls[3] = {0.f, 0.f, 0.f};
    for (int l = 0; l < 3; ++l) {
        for (int s = 0; s < 32; ++s) {
            obj[l] += acc[ACC_OBJ + l * 32 + s];
            cls[l] += acc[ACC_CLS + l * 32 + s];
        }
    }
    float box_l = acc[0] / (float)n0 + acc[1] / (float)n1 + acc[2] / (float)n2;
    float obj_l = 0.4f * obj[0] / (float)c0
                + 1.0f * obj[1] / (float)c1
                + 4.0f * obj[2] / (float)c2;
    float cls_l = cls[0] / ((float)n0 * NC)
                + cls[1] / ((float)n1 * NC)
                + cls[2] / ((float)n2 * NC);
    out[0] = 0.05f * box_l + 1.0f * obj_l + 0.5f * cls_l;
}

extern "C" void kernel_launch(void* const* d_in, const int* in_sizes, int n_in,
                              void* d_out, int out_size, void* d_ws, size_t ws_size,
                              hipStream_t stream) {
    (void)n_in; (void)out_size; (void)ws_size;
    char* ws = (char*)d_ws;

    Args A;
    int n[3], g[3], cells[3];
    size_t off = ACC_FLOATS * 4;           // 1KB header: partial-sum slots
    size_t winner_off[3], cnt_off[3], iou_off[3];

    for (int i = 0; i < 3; ++i) {
        n[i] = in_sizes[8 * i + 1];
        int gg = in_sizes[8 * i] / (BS * 255);
        int gv = (int)(sqrt((double)gg) + 0.5);
        g[i] = gv;
        cells[i] = BS * NA * gv * gv;
        winner_off[i] = off; off += (size_t)cells[i] * 4;
        cnt_off[i]    = off; off += (size_t)cells[i] * 4;
    }
    size_t zero_bytes = off;               // accumulators + winner + cnt
    for (int i = 0; i < 3; ++i) { iou_off[i] = off; off += (size_t)n[i] * 4; }

    for (int i = 0; i < 3; ++i) {
        Layer& L = A.L[i];
        L.pred = (const float*)d_in[8 * i + 0];
        L.b    = (const int*)  d_in[8 * i + 1];
        L.a    = (const int*)  d_in[8 * i + 2];
        L.gj   = (const int*)  d_in[8 * i + 3];
        L.gi   = (const int*)  d_in[8 * i + 4];
        L.tbox = (const float*)d_in[8 * i + 5];
        L.tcls = (const int*)  d_in[8 * i + 6];
        L.anc  = (const float*)d_in[8 * i + 7];
        L.winner = (unsigned int*)(ws + winner_off[i]);
        L.cnt    = (unsigned int*)(ws + cnt_off[i]);
        L.iou    = (float*)(ws + iou_off[i]);
        L.g = g[i];
        L.n = n[i];
    }
    float* acc = (float*)ws;

    hipMemsetAsync(d_ws, 0, zero_bytes, stream);

    // entry kernel: CIoU + scatter winner/cnt + tcls gather
    {
        int b0 = (n[0] + 255) / 256, b1 = (n[1] + 255) / 256, b2 = (n[2] + 255) / 256;
        A.cum0 = b0; A.cum1 = b0 + b1;
        entry_kernel<<<b0 + b1 + b2, 256, 0, stream>>>(A, acc);
    }
    // dense scan: (cell-group x 8 channel-chunks) blocks per layer
    {
        int s0 = ((cells[0] + 1023) / 1024) * 8;
        int s1 = ((cells[1] + 1023) / 1024) * 8;
        int s2 = ((cells[2] + 1023) / 1024) * 8;
        A.cum0 = s0; A.cum1 = s0 + s1;
        scan_kernel<<<s0 + s1 + s2, 256, 0, stream>>>(A, acc);
    }
    final_kernel<<<1, 1, 0, stream>>>(acc, (float*)d_out,
                                      n[0], n[1], n[2],
                                      cells[0], cells[1], cells[2]);
}